// Round 10
// baseline (385.723 us; speedup 1.0000x reference)
//
#include <hip/hip_runtime.h>
#include <hip/hip_bf16.h>

// MPNN on MI355X.
// Identities: (1) (sum_e relu(a+b)) @ w2 pulls w2 out of the edge sum; (2) lin GEMM composed
// into w1 GEMM via W12c = lin_w@w1 (MFMA compose_kernel).
// b-half of the edge operand stored FP8 e4m3 (6.4MB working set); a f16; accumulate f32.
// CSR: deterministic counting sort (LDS-rank, bucket-local). Atomic CSR regressed (R15).
// R11: glds16 staging. 483->409. R13: persistent 2-phase GEMMs ->388.
// R14: gather+gemm8 tile-fusion regressed (gather needs max TLP). Reverted.
// R17: pool contention fix (1 atomic/col/block via gstart). 413->379.6.
// R18: layer-boundary fusion gemm8(l)+gemm16(l+1) (xb never leaves LDS). ->369.7. BEST.
// R19: gemm8+pool fusion REGRESSED (+8us): added 4-8 full-block barriers/tile + reduce work
// on the GEMM critical path to save only ~8us of streaming pool+xb-write. Lesson: fusion
// pays only when it deletes >=10us dispatch or >=10MB traffic WITHOUT adding barriers.
// R20: revert gemm8_pool -> R18 tail (gemm_persist<8> + pool_kernel + final); KEEP R19's
// part2/scanb last-finisher merge (one dispatch deleted, mechanism sound).

typedef _Float16 f16_t;
typedef f16_t f16x2 __attribute__((ext_vector_type(2)));
typedef f16_t f16x8 __attribute__((ext_vector_type(8)));
typedef float f32x4 __attribute__((ext_vector_type(4)));
typedef float f32x2v __attribute__((ext_vector_type(2)));
typedef unsigned int u32;
typedef unsigned short u16;
typedef unsigned char u8;

__device__ __forceinline__ float f16lo(u32 v) {
    return (float)__builtin_bit_cast(f16_t, (u16)(v & 0xffff));
}
__device__ __forceinline__ float f16hi(u32 v) {
    return (float)__builtin_bit_cast(f16_t, (u16)(v >> 16));
}
__device__ __forceinline__ u16 f16b(float x) { return __builtin_bit_cast(u16, (f16_t)x); }
__device__ __forceinline__ u32 f16pack(float x, float y) {
    return (u32)f16b(x) | ((u32)f16b(y) << 16);
}

// async global->LDS, 16B per lane; LDS dest must be wave-uniform base (+lane*16 implicit)
typedef __attribute__((address_space(1))) void gvoid_t;
typedef __attribute__((address_space(3))) void lvoid_t;
__device__ __forceinline__ void glds16(const void* g, void* l) {
    __builtin_amdgcn_global_load_lds((gvoid_t*)g, (lvoid_t*)l, 16, 0, 0);
}

// ---------------- fused prep: transposes | lin_w->f16 | bias | hist | gstart | convx -------
struct PrepArgs {
    const float* x; f16_t* xb; int totalx;
    const int* ei; int E;
    int* hist; int nbk; int NB;
    const int* batch; int* gstart; int N; int G; int nBat;
    const float* lin_w[3]; const float* lin_b[3];
    const float* w1[3]; const float* b1[3]; const float* w2[3];
    f16_t* linw16;   // [3][128][128] f16 copy of lin_w
    f16_t* w1T;      // [3][256][128]: w1T[j][c] = w1sel(c,j)
    f16_t* W2t;      // [3][128][128]: W2t[j][k] = w2[k][j]
    float* bias256c; // [3][256]
};

__global__ __launch_bounds__(256) void prep_kernel(PrepArgs A, int nConvB) {
    __shared__ union { int hist[512]; u16 T16[128 * 130]; } shm;
    const int b = blockIdx.x, tid = threadIdx.x;
    const int nTr = 9, nLw = 48, nBias = 3;
    if (b < nTr) {
        // LDS-tiled 128x128 transpose -> f16. which: 0=w1 top, 1=w1 bottom, 2=w2
        int layer = b / 3, which = b % 3;
        const float* src; f16_t* dst;
        if (which == 0)      { src = A.w1[layer];          dst = A.w1T + layer * 32768; }
        else if (which == 1) { src = A.w1[layer] + 16384;  dst = A.w1T + layer * 32768 + 16384; }
        else                 { src = A.w2[layer];          dst = A.W2t + layer * 16384; }
#pragma unroll
        for (int it = 0; it < 16; ++it) {
            int idx = it * 1024 + tid * 4;     // coalesced float4 read
            int r = idx >> 7, c = idx & 127;
            float4 v = *(const float4*)(src + idx);
            *(u32*)&shm.T16[r * 130 + c] = f16pack(v.x, v.y);
            *(u32*)&shm.T16[r * 130 + c + 2] = f16pack(v.z, v.w);
        }
        __syncthreads();
#pragma unroll
        for (int it = 0; it < 32; ++it) {      // 32*256 = 8192 u32 outputs
            int o = it * 256 + tid;            // u32 output index: j*64 + c2
            int j = o >> 6, c = (o & 63) * 2;
            u32 w = (u32)shm.T16[c * 130 + j] | ((u32)shm.T16[(c + 1) * 130 + j] << 16);
            ((u32*)dst)[o] = w;                // dst[j][c], coalesced
        }
        return;
    }
    if (b < nTr + nLw) {
        int i = (b - nTr) * 1024 + tid * 4;    // over 3*16384 f32
        int layer = i >> 14, off = i & 16383;
        float4 v = *(const float4*)(A.lin_w[layer] + off);
        *(uint2*)(A.linw16 + i) = make_uint2(f16pack(v.x, v.y), f16pack(v.z, v.w));
        return;
    }
    if (b < nTr + nLw + nBias) {
        int layer = b - nTr - nLw;
        int j = tid;  // 256 threads
        const float* w1p = A.w1[layer];
        const float* wcol = (j < 128) ? (w1p + j) : (w1p + 16384 + (j - 128));
        const float* lbp = A.lin_b[layer];
        float s = (j < 128) ? A.b1[layer][j] : 0.f;
        for (int c = 0; c < 128; ++c) s += lbp[c] * wcol[c * 128];  // coalesced across lanes
        A.bias256c[layer * 256 + j] = s;
        return;
    }
    if (b < nTr + nLw + nBias + A.NB) {
        // edge histogram: bucket = dst>>7, LDS counters only
        const int bb = b - nTr - nLw - nBias;
        const int nbk = A.nbk, E = A.E;
        for (int i = tid; i < nbk; i += 256) shm.hist[i] = 0;
        __syncthreads();
        const int chunk = (E + A.NB - 1) / A.NB;
        const int e0 = bb * chunk, e1 = min(E, e0 + chunk);
        for (int e = e0 + tid; e < e1; e += 256) atomicAdd(&shm.hist[A.ei[E + e] >> 7], 1);
        __syncthreads();
        for (int i = tid; i < nbk; i += 256) A.hist[(size_t)bb * nbk + i] = shm.hist[i];
        return;
    }
    if (b < nTr + nLw + nBias + A.NB + A.nBat) {
        // gstart[g] = first node of graph g (batch sorted). Transition scan.
        int n = (b - nTr - nLw - nBias - A.NB) * 256 + tid;
        if (n >= A.N) return;
        int b1 = A.batch[n];
        if (n == 0) {
            for (int g = 0; g <= b1; ++g) A.gstart[g] = 0;
        } else {
            int b0 = A.batch[n - 1];
            if (b0 != b1)
                for (int g = b0 + 1; g <= b1; ++g) A.gstart[g] = n;
        }
        if (n == A.N - 1)
            for (int g = b1 + 1; g <= A.G; ++g) A.gstart[g] = A.N;
        return;
    }
    // convx: fp32 -> f16
    int i = ((b - nTr - nLw - nBias - A.NB - A.nBat) * 256 + tid) * 4;
    if (i >= A.totalx) return;
    float4 v = *(const float4*)(A.x + i);
    *(uint2*)(A.xb + i) = make_uint2(f16pack(v.x, v.y), f16pack(v.z, v.w));
}

// ---------------- hscan: per-bucket exclusive scan of per-block counts ----------------
__global__ __launch_bounds__(256) void hscan_kernel(int* __restrict__ hist,
                                                    int* __restrict__ bcnt, int nbk, int NB) {
    __shared__ int sh[256];
    const int b = blockIdx.x, t = threadIdx.x;
    int run = 0;
    for (int c0 = 0; c0 < NB; c0 += 256) {
        int idx = c0 + t;
        int v = (idx < NB) ? hist[(size_t)idx * nbk + b] : 0;
        sh[t] = v;
        __syncthreads();
#pragma unroll
        for (int o = 1; o < 256; o <<= 1) {
            int u = (t >= o) ? sh[t - o] : 0;
            __syncthreads();
            sh[t] += u;
            __syncthreads();
        }
        if (idx < NB) hist[(size_t)idx * nbk + b] = run + sh[t] - v;
        int tot = sh[255];
        __syncthreads();
        run += tot;
    }
    if (t == 0) bcnt[b] = run;
}

// ---------------- scat: packed (dst&127)<<16|src at precomputed base + LDS rank ------------
__global__ __launch_bounds__(256) void scat_kernel(const int* __restrict__ ei,
                                                   const int* __restrict__ hist,
                                                   u32* __restrict__ bbuf, int E, int NB,
                                                   int nbk, int cap) {
    __shared__ int basep[512];
    __shared__ int cnt2[512];
    const int bb = blockIdx.x, t = threadIdx.x;
    for (int i = t; i < nbk; i += 256) {
        basep[i] = hist[(size_t)bb * nbk + i];
        cnt2[i] = 0;
    }
    __syncthreads();
    const int chunk = (E + NB - 1) / NB;
    const int e0 = bb * chunk, e1 = min(E, e0 + chunk);
    for (int e = e0 + t; e < e1; e += 256) {
        int dst = ei[E + e], src = ei[e];
        int bkt = dst >> 7;
        int r = atomicAdd(&cnt2[bkt], 1);  // LDS returning atomic: cheap
        int pp = basep[bkt] + r;
        if (pp < cap) bbuf[(size_t)bkt * cap + pp] = ((u32)(dst & 127) << 16) | (u32)src;
    }
}

// ---------------- part2: per-bucket degree + local scan; last finisher inlines scanB -------
__global__ __launch_bounds__(128) void part2_kernel(const u32* __restrict__ bbuf,
                                                    const int* __restrict__ bcnt,
                                                    int* __restrict__ row_ptr,
                                                    float* __restrict__ cntp1f,
                                                    int* __restrict__ bsumB,
                                                    int* __restrict__ bbase,
                                                    int* __restrict__ done,
                                                    int cap, int N, int nbk) {
    __shared__ int ldeg[128];
    __shared__ int sh[128];
    __shared__ int lastflag;
    const int b = blockIdx.x, t = threadIdx.x;
    ldeg[t] = 0;
    __syncthreads();
    const int cnt = min(bcnt[b], cap);
    const u32* p = bbuf + (size_t)b * cap;
    for (int i = t; i < cnt; i += 128) atomicAdd(&ldeg[p[i] >> 16], 1);
    __syncthreads();
    int d = ldeg[t];
    sh[t] = d;
    __syncthreads();
#pragma unroll
    for (int o = 1; o < 128; o <<= 1) {
        int u = (t >= o) ? sh[t - o] : 0;
        __syncthreads();
        sh[t] += u;
        __syncthreads();
    }
    int node = (b << 7) + t;
    if (node < N) {
        row_ptr[node] = sh[t] - d;
        cntp1f[node] = (float)(d + 1);
    }
    if (t == 127) bsumB[b] = sh[127];
    // ---- last-finisher does the bucket-total scan (no spin: only the last block works) ----
    __threadfence();
    __syncthreads();
    if (t == 0) lastflag = (atomicAdd(done, 1) == (int)gridDim.x - 1);
    __syncthreads();
    if (!lastflag) return;
    __threadfence();  // acquire all bsumB
    int run = 0;
    for (int c0 = 0; c0 < nbk; c0 += 128) {
        int idx = c0 + t;
        int v = (idx < nbk) ? bsumB[idx] : 0;
        sh[t] = v;
        __syncthreads();
#pragma unroll
        for (int o = 1; o < 128; o <<= 1) {
            int u = (t >= o) ? sh[t - o] : 0;
            __syncthreads();
            sh[t] += u;
            __syncthreads();
        }
        if (idx < nbk) bbase[idx] = run + sh[t] - v;
        run += sh[127];
        __syncthreads();
    }
    if (t == 0) row_ptr[N] = run;
}

// ---------------- part3: finalize row_ptr, scatter u16 colarr ----------------
__global__ __launch_bounds__(128) void part3_kernel(const u32* __restrict__ bbuf,
                                                    const int* __restrict__ bcnt,
                                                    const int* __restrict__ bbase,
                                                    int* __restrict__ row_ptr,
                                                    u16* __restrict__ colarr, int cap, int N) {
    __shared__ int lcur[128];
    const int b = blockIdx.x, t = threadIdx.x;
    const int node = (b << 7) + t;
    const int bb = bbase[b];
    int rp = 0;
    if (node < N) {
        rp = row_ptr[node] + bb;
        row_ptr[node] = rp;
    }
    lcur[t] = rp;
    __syncthreads();
    const int cnt = min(bcnt[b], cap);
    const u32* p = bbuf + (size_t)b * cap;
    for (int i = t; i < cnt; i += 128) {
        u32 en = p[i];
        int addr = atomicAdd(&lcur[en >> 16], 1);
        colarr[addr] = (u16)(en & 0xffffu);
    }
}

// ---------------- one-shot MFMA tile (compose only): Y[128x128] = X @ Wt^T -----------------
__device__ __forceinline__ void gemm_tile(const f16_t* __restrict__ X,
                                          const f16_t* __restrict__ Wt,
                                          f16_t* __restrict__ Y, int N,
                                          int ldc, int row0) {
    __shared__ f16_t sX[128 * 128];
    __shared__ f16_t sW[128 * 128];
    const int tid = threadIdx.x;
    const int wave = tid >> 6, lane = tid & 63;
#pragma unroll
    for (int it = 0; it < 8; ++it) {
        int idx = it * 256 + tid;
        int r = idx >> 4, c8 = idx & 15;
        int gr = row0 + r;
        if (gr >= N) gr = 0;
        glds16(X + (size_t)gr * 128 + ((c8 ^ (r & 7)) * 8),
               sX + (size_t)(it * 256 + (wave << 6)) * 8);
    }
#pragma unroll
    for (int it = 0; it < 8; ++it) {
        int idx = it * 256 + tid;
        int r = idx >> 4, c8 = idx & 15;
        glds16(Wt + (size_t)r * 128 + ((c8 ^ (r & 7)) * 8),
               sW + (size_t)(it * 256 + (wave << 6)) * 8);
    }
    __syncthreads();
    const int m = lane & 15, q = lane >> 4;
    const int sw = m & 7;
    f32x4 acc[2][8];
#pragma unroll
    for (int rt = 0; rt < 2; ++rt)
#pragma unroll
        for (int t = 0; t < 8; ++t) acc[rt][t] = (f32x4){0.f, 0.f, 0.f, 0.f};
#pragma unroll
    for (int kk = 0; kk < 4; ++kk) {
        const int g = (kk * 4 + q) ^ sw;
        f16x8 a0 = *(const f16x8*)(&sX[(wave * 32 + m) * 128 + g * 8]);
        f16x8 a1 = *(const f16x8*)(&sX[(wave * 32 + 16 + m) * 128 + g * 8]);
#pragma unroll
        for (int t = 0; t < 8; ++t) {
            f16x8 bfr = *(const f16x8*)(&sW[(t * 16 + m) * 128 + g * 8]);
            acc[0][t] = __builtin_amdgcn_mfma_f32_16x16x32_f16(a0, bfr, acc[0][t], 0, 0, 0);
            acc[1][t] = __builtin_amdgcn_mfma_f32_16x16x32_f16(a1, bfr, acc[1][t], 0, 0, 0);
        }
    }
#pragma unroll
    for (int t = 0; t < 8; ++t) {
        int col = t * 16 + m;
#pragma unroll
        for (int rt = 0; rt < 2; ++rt) {
#pragma unroll
            for (int j = 0; j < 4; ++j) {
                int r = row0 + wave * 32 + rt * 16 + q * 4 + j;
                if (r < N) Y[(size_t)r * ldc + col] = (f16_t)acc[rt][t][j];
            }
        }
    }
}

// compose: W12ct[layer][j][k] = sum_c w1T[layer][j][c] * linw16[layer][k][c]  (MFMA)
__global__ __launch_bounds__(256) void compose_kernel(const f16_t* __restrict__ w1T,
                                                      const f16_t* __restrict__ linw16,
                                                      f16_t* __restrict__ W12ct) {
    int layer = blockIdx.x >> 1, rb = blockIdx.x & 1;
    gemm_tile(w1T + layer * 32768, linw16 + layer * 16384, W12ct + layer * 32768, 256, 128,
              rb * 128);
}

// ---------------- persistent 2-phase node GEMM ----------------
// NT=16: Y[N][0..127]=f16 aArr, cols 128..255 -> fp8 Y8. NT=8: Y[N][0..127] f16 only.
template <int NT>
__global__ __launch_bounds__(512, 1) void gemm_persist(
    const f16_t* __restrict__ X, const f16_t* __restrict__ Wt,
    const float* __restrict__ bias, const float* __restrict__ bias2,
    const float* __restrict__ rowscale, f16_t* __restrict__ Y, u8* __restrict__ Y8,
    int N, int relu_flag, int ntiles) {
    __shared__ f16_t sW[NT * 16 * 128];
    __shared__ f16_t sX[2][128 * 128];
    const int tid = threadIdx.x;
    const int wave = tid >> 6, lane = tid & 63;
    const int m = lane & 15, q = lane >> 4, sw = m & 7;
    constexpr int NR = (NT == 16) ? 2 : 1;
    const int rb0 = (NT == 16) ? ((wave & 3) * 32) : (wave * 16);
    const int chalf = (NT == 16) ? (wave >> 2) : 0;

    // stage W once (resident for whole kernel). NT*16 rows x 16 chunks = NT/2 * 512 chunks.
#pragma unroll
    for (int it = 0; it < NT / 2; ++it) {
        int idx = it * 512 + tid;
        int r = idx >> 4, c8 = idx & 15;
        glds16(Wt + (size_t)r * 128 + ((c8 ^ (r & 7)) * 8),
               sW + (size_t)(it * 512 + (wave << 6)) * 8);
    }
    // hoist per-lane column bias (tile-invariant)
    float bvv[8], b2vv[8];
#pragma unroll
    for (int t2 = 0; t2 < 8; ++t2) {
        int colb = chalf * 128 + t2 * 16 + m;
        bvv[t2] = bias ? bias[colb] : 0.f;
        b2vv[t2] = bias2 ? bias2[colb] : 0.f;
    }
    // stage first tile into buf0
    int t = blockIdx.x;
    {
        int row0 = t * 128;
#pragma unroll
        for (int it = 0; it < 4; ++it) {
            int idx = it * 512 + tid;
            int r = idx >> 4, c8 = idx & 15;
            int gr = row0 + r;
            if (gr >= N) gr = 0;
            glds16(X + (size_t)gr * 128 + ((c8 ^ (r & 7)) * 8),
                   sX[0] + (size_t)(it * 512 + (wave << 6)) * 8);
        }
    }
    __syncthreads();
    int cur = 0;
    for (; t < ntiles; t += gridDim.x) {
        const int row0 = t * 128;
        const int tn = t + gridDim.x;
        f16_t* sXc = sX[cur];
        if (tn < ntiles) {  // prefetch next tile while computing this one
            const int r0n = tn * 128;
            f16_t* sXn = sX[cur ^ 1];
#pragma unroll
            for (int it = 0; it < 4; ++it) {
                int idx = it * 512 + tid;
                int r = idx >> 4, c8 = idx & 15;
                int gr = r0n + r;
                if (gr >= N) gr = 0;
                glds16(X + (size_t)gr * 128 + ((c8 ^ (r & 7)) * 8),
                       sXn + (size_t)(it * 512 + (wave << 6)) * 8);
            }
        }
        f32x4 acc[NR][8];
#pragma unroll
        for (int rt = 0; rt < NR; ++rt)
#pragma unroll
            for (int t2 = 0; t2 < 8; ++t2) acc[rt][t2] = (f32x4){0.f, 0.f, 0.f, 0.f};
#pragma unroll
        for (int kk = 0; kk < 4; ++kk) {
            const int g = (kk * 4 + q) ^ sw;
            f16x8 a0 = *(const f16x8*)(&sXc[(rb0 + m) * 128 + g * 8]);
            f16x8 a1{};
            if constexpr (NR == 2) a1 = *(const f16x8*)(&sXc[(rb0 + 16 + m) * 128 + g * 8]);
#pragma unroll
            for (int t2 = 0; t2 < 8; ++t2) {
                f16x8 bfr =
                    *(const f16x8*)(&sW[(size_t)(chalf * 128 + t2 * 16 + m) * 128 + g * 8]);
                acc[0][t2] = __builtin_amdgcn_mfma_f32_16x16x32_f16(a0, bfr, acc[0][t2], 0, 0, 0);
                if constexpr (NR == 2)
                    acc[1][t2] =
                        __builtin_amdgcn_mfma_f32_16x16x32_f16(a1, bfr, acc[1][t2], 0, 0, 0);
            }
        }
        if (NT == 16) __syncthreads();  // waves w and w+4 share X rows: wait before overwrite
        // epilogue: wave-private 16-row LDS region in the consumed buffer, vector stores
        f16_t* region = sXc + wave * 16 * 128;
#pragma unroll
        for (int rt = 0; rt < NR; ++rt) {
            float rs[4];
#pragma unroll
            for (int j = 0; j < 4; ++j) {
                int gr = row0 + rb0 + rt * 16 + q * 4 + j;
                rs[j] = (bias2 && gr < N) ? rowscale[gr] : 0.f;
            }
#pragma unroll
            for (int t2 = 0; t2 < 8; ++t2) {
#pragma unroll
                for (int j = 0; j < 4; ++j) {
                    int rl2 = q * 4 + j;
                    float v = acc[rt][t2][j] + bvv[t2];
                    if (bias2) v += rs[j] * b2vv[t2];
                    if (relu_flag) v = fmaxf(v, 0.f);
                    region[rl2 * 128 + ((t2 * 16 + m) ^ ((rl2 & 4) << 3))] = (f16_t)v;
                }
            }
#pragma unroll
            for (int it2 = 0; it2 < 4; ++it2) {
                int i = it2 * 64 + lane;
                int rl = i >> 4, c8 = i & 15;
                int gr = row0 + rb0 + rt * 16 + rl;
                const f16_t* rp = &region[rl * 128 + ((c8 ^ (rl & 4)) * 8)];
                if (NT == 16 && chalf == 1) {
                    const u32* p = (const u32*)rp;
                    u32 lo = __builtin_amdgcn_cvt_pk_fp8_f32(f16lo(p[0]), f16hi(p[0]), 0u, false);
                    lo = __builtin_amdgcn_cvt_pk_fp8_f32(f16lo(p[1]), f16hi(p[1]), lo, true);
                    u32 hi = __builtin_amdgcn_cvt_pk_fp8_f32(f16lo(p[2]), f16hi(p[2]), 0u, false);
                    hi = __builtin_amdgcn_cvt_pk_fp8_f32(f16lo(p[3]), f16hi(p[3]), hi, true);
                    if (gr < N) *(uint2*)(Y8 + (size_t)gr * 128 + c8 * 8) = make_uint2(lo, hi);
                } else {
                    uint4 v4 = *(const uint4*)rp;
                    if (gr < N) *(uint4*)(Y + (size_t)gr * 128 + c8 * 8) = v4;
                }
            }
        }
        __syncthreads();  // drains prefetch vmcnt + syncs epilogue before next overwrite
        cur ^= 1;
    }
}

// -------- fused layer boundary: xb=relu(q@W2t+(deg+1)b2) -> [a|b8]=xb@W12c+bias ----------
__global__ __launch_bounds__(512, 1) void fused_g8_g16(
    const f16_t* __restrict__ q, const f16_t* __restrict__ W2t,
    const float* __restrict__ b2, const float* __restrict__ cntp1f,
    const f16_t* __restrict__ W12ct, const float* __restrict__ bias16,
    f16_t* __restrict__ aArr, u8* __restrict__ Y8, int N, int ntiles) {
    __shared__ f16_t sW2[128 * 128];    // 32KB, resident
    __shared__ f16_t sW12[256 * 128];   // 64KB, resident
    __shared__ f16_t sX[128 * 128];     // 32KB, per-tile (q -> xb -> epilogue scratch)
    const int tid = threadIdx.x;
    const int wave = tid >> 6, lane = tid & 63;
    const int m = lane & 15, qd = lane >> 4, sw = m & 7;
    const int chalf = wave >> 2, rb0c = (wave & 3) * 32;

    // stage both W's once
#pragma unroll
    for (int it = 0; it < 4; ++it) {
        int idx = it * 512 + tid;
        int r = idx >> 4, c8 = idx & 15;
        glds16(W2t + (size_t)r * 128 + ((c8 ^ (r & 7)) * 8),
               sW2 + (size_t)(it * 512 + (wave << 6)) * 8);
    }
#pragma unroll
    for (int it = 0; it < 8; ++it) {
        int idx = it * 512 + tid;
        int r = idx >> 4, c8 = idx & 15;
        glds16(W12ct + (size_t)r * 128 + ((c8 ^ (r & 7)) * 8),
               sW12 + (size_t)(it * 512 + (wave << 6)) * 8);
    }
    // hoist biases
    float b2v[8], bv16[8];
#pragma unroll
    for (int t2 = 0; t2 < 8; ++t2) {
        b2v[t2] = b2[t2 * 16 + m];
        bv16[t2] = bias16[chalf * 128 + t2 * 16 + m];
    }

    for (int t = blockIdx.x; t < ntiles; t += gridDim.x) {
        const int row0 = t * 128;
        // stage q tile
#pragma unroll
        for (int it = 0; it < 4; ++it) {
            int idx = it * 512 + tid;
            int r = idx >> 4, c8 = idx & 15;
            int gr = row0 + r;
            if (gr >= N) gr = 0;
            glds16(q + (size_t)gr * 128 + ((c8 ^ (r & 7)) * 8),
                   sX + (size_t)(it * 512 + (wave << 6)) * 8);
        }
        __syncthreads();  // drains q (and W on first iteration)

        // ---- Phase B: xb rows wave*16..+15 = relu(q @ W2t + (deg+1)*b2) ----
        f32x4 accB[8];
#pragma unroll
        for (int t2 = 0; t2 < 8; ++t2) accB[t2] = (f32x4){0.f, 0.f, 0.f, 0.f};
#pragma unroll
        for (int kk = 0; kk < 4; ++kk) {
            const int g = (kk * 4 + qd) ^ sw;
            f16x8 a0 = *(const f16x8*)(&sX[(wave * 16 + m) * 128 + g * 8]);
#pragma unroll
            for (int t2 = 0; t2 < 8; ++t2) {
                f16x8 bfr = *(const f16x8*)(&sW2[(t2 * 16 + m) * 128 + g * 8]);
                accB[t2] = __builtin_amdgcn_mfma_f32_16x16x32_f16(a0, bfr, accB[t2], 0, 0, 0);
            }
        }
        // epilogue B: write xb into own rows of sX in staging layout (own A-reads are done)
        float rs[4];
#pragma unroll
        for (int j = 0; j < 4; ++j) {
            int gr = row0 + wave * 16 + qd * 4 + j;
            rs[j] = (gr < N) ? cntp1f[gr] : 0.f;
        }
#pragma unroll
        for (int t2 = 0; t2 < 8; ++t2) {
#pragma unroll
            for (int j = 0; j < 4; ++j) {
                int rr = wave * 16 + qd * 4 + j;
                float v = fmaxf(accB[t2][j] + rs[j] * b2v[t2], 0.f);
                sX[rr * 128 + (((2 * t2 + (m >> 3)) ^ (rr & 7)) * 8 + (m & 7))] = (f16_t)v;
            }
        }
        __syncthreads();  // xb tile visible to all waves

        // ---- Phase C: [a|b8] rows rb0c..+31, cols chalf*128..+127 = xb @ W12c + bias ----
        f32x4 accC[2][8];
#pragma unroll
        for (int rt = 0; rt < 2; ++rt)
#pragma unroll
            for (int t2 = 0; t2 < 8; ++t2) accC[rt][t2] = (f32x4){0.f, 0.f, 0.f, 0.f};
#pragma unroll
        for (int kk = 0; kk < 4; ++kk) {
            const int g = (kk * 4 + qd) ^ sw;
            f16x8 a0 = *(const f16x8*)(&sX[(rb0c + m) * 128 + g * 8]);
            f16x8 a1 = *(const f16x8*)(&sX[(rb0c + 16 + m) * 128 + g * 8]);
#pragma unroll
            for (int t2 = 0; t2 < 8; ++t2) {
                f16x8 bfr =
                    *(const f16x8*)(&sW12[(size_t)(chalf * 128 + t2 * 16 + m) * 128 + g * 8]);
                accC[0][t2] = __builtin_amdgcn_mfma_f32_16x16x32_f16(a0, bfr, accC[0][t2], 0, 0, 0);
                accC[1][t2] = __builtin_amdgcn_mfma_f32_16x16x32_f16(a1, bfr, accC[1][t2], 0, 0, 0);
            }
        }
        __syncthreads();  // all xb reads done before scratch overwrite

        // epilogue C: wave-private 16-row scratch region, vector stores (same as persist<16>)
        f16_t* region = sX + wave * 16 * 128;
#pragma unroll
        for (int rt = 0; rt < 2; ++rt) {
#pragma unroll
            for (int t2 = 0; t2 < 8; ++t2) {
#pragma unroll
                for (int j = 0; j < 4; ++j) {
                    int rl2 = qd * 4 + j;
                    float v = accC[rt][t2][j] + bv16[t2];
                    region[rl2 * 128 + ((t2 * 16 + m) ^ ((rl2 & 4) << 3))] = (f16_t)v;
                }
            }
#pragma unroll
            for (int it2 = 0; it2 < 4; ++it2) {
                int i = it2 * 64 + lane;
                int rl = i >> 4, c8 = i & 15;
                int gr = row0 + rb0c + rt * 16 + rl;
                const f16_t* rp = &region[rl * 128 + ((c8 ^ (rl & 4)) * 8)];
                if (chalf == 1) {
                    const u32* p = (const u32*)rp;
                    u32 lo = __builtin_amdgcn_cvt_pk_fp8_f32(f16lo(p[0]), f16hi(p[0]), 0u, false);
                    lo = __builtin_amdgcn_cvt_pk_fp8_f32(f16lo(p[1]), f16hi(p[1]), lo, true);
                    u32 hi = __builtin_amdgcn_cvt_pk_fp8_f32(f16lo(p[2]), f16hi(p[2]), 0u, false);
                    hi = __builtin_amdgcn_cvt_pk_fp8_f32(f16lo(p[3]), f16hi(p[3]), hi, true);
                    if (gr < N) *(uint2*)(Y8 + (size_t)gr * 128 + c8 * 8) = make_uint2(lo, hi);
                } else {
                    uint4 v4 = *(const uint4*)rp;
                    if (gr < N) *(uint4*)(aArr + (size_t)gr * 128 + c8 * 8) = v4;
                }
            }
        }
        __syncthreads();  // scratch free before next tile staging
    }
}

// ---------------- gather: a f16, b fp8, f32 accum; predicated 16-wide (4 loads deep) -------
__global__ __launch_bounds__(256) void gather_kernel(const f16_t* __restrict__ aArr,
                                                     const u8* __restrict__ b8,
                                                     const int* __restrict__ row_ptr,
                                                     const u16* __restrict__ colarr,
                                                     f16_t* __restrict__ q, int N) {
    int wid = (blockIdx.x * 256 + threadIdx.x) >> 6;
    int lane = threadIdx.x & 63;
    if (wid >= N) return;
    const int g = lane >> 4, l = lane & 15;
    uint4 A = ((const uint4*)aArr)[(size_t)wid * 16 + l];
    float a0 = f16lo(A.x), a1 = f16hi(A.x), a2 = f16lo(A.y), a3 = f16hi(A.y);
    float a4 = f16lo(A.z), a5 = f16hi(A.z), a6 = f16lo(A.w), a7 = f16hi(A.w);
    float c0 = 0.f, c1 = 0.f, c2 = 0.f, c3 = 0.f, c4 = 0.f, c5 = 0.f, c6 = 0.f, c7 = 0.f;
    const uint2* b8u = (const uint2*)b8;  // row = 16 uint2
    auto accum = [&](uint2 B) {
        f32x2v p0 = __builtin_amdgcn_cvt_pk_f32_fp8(B.x, false);
        f32x2v p1 = __builtin_amdgcn_cvt_pk_f32_fp8(B.x, true);
        f32x2v p2 = __builtin_amdgcn_cvt_pk_f32_fp8(B.y, false);
        f32x2v p3 = __builtin_amdgcn_cvt_pk_f32_fp8(B.y, true);
        c0 += fmaxf(a0 + p0.x, 0.f); c1 += fmaxf(a1 + p0.y, 0.f);
        c2 += fmaxf(a2 + p1.x, 0.f); c3 += fmaxf(a3 + p1.y, 0.f);
        c4 += fmaxf(a4 + p2.x, 0.f); c5 += fmaxf(a5 + p2.y, 0.f);
        c6 += fmaxf(a6 + p3.x, 0.f); c7 += fmaxf(a7 + p3.y, 0.f);
    };
    if (g == 0) accum(b8u[(size_t)wid * 16 + l]);  // self loop
    const int e0 = row_ptr[wid], e1 = row_ptr[wid + 1];
    for (int e = e0; e < e1; e += 16) {  // predicated: always 4 colarr+4 row loads in flight
#pragma unroll
        for (int s = 0; s < 4; ++s) {
            int idx = e + s * 4 + g;
            int src = colarr[min(idx, e1 - 1)];        // clamped: always a valid edge
            uint2 B = b8u[(size_t)src * 16 + l];
            if (idx < e1) accum(B);                    // masked accumulate
        }
    }
#pragma unroll
    for (int off = 16; off < 64; off <<= 1) {
        c0 += __shfl_xor(c0, off); c1 += __shfl_xor(c1, off);
        c2 += __shfl_xor(c2, off); c3 += __shfl_xor(c3, off);
        c4 += __shfl_xor(c4, off); c5 += __shfl_xor(c5, off);
        c6 += __shfl_xor(c6, off); c7 += __shfl_xor(c7, off);
    }
    if (g == 0) {
        uint4 o;
        o.x = f16pack(c0, c1); o.y = f16pack(c2, c3);
        o.z = f16pack(c4, c5); o.w = f16pack(c6, c7);
        ((uint4*)q)[(size_t)wid * 16 + l] = o;
    }
}

// ---------------- pooling: 8 blocks/graph, contiguous streaming, 1 atomic/col/block -------
__global__ __launch_bounds__(256) void pool_kernel(const f16_t* __restrict__ agg,
                                                   const int* __restrict__ gstart,
                                                   float* __restrict__ pooled) {
    __shared__ float red[4][128];
    const int g = blockIdx.x >> 3, part = blockIdx.x & 7;
    const int tid = threadIdx.x, wave = tid >> 6, lane = tid & 63;
    const int lo = gstart[g], hi = gstart[g + 1];
    const int cnt = hi - lo;
    const int len = (cnt + 7) >> 3;
    const int n0 = lo + part * len, n1 = min(hi, n0 + len);
    const u32* au = (const u32*)agg;
    float sx = 0.f, sy = 0.f;
#pragma unroll 4
    for (int n = n0 + wave; n < n1; n += 4) {
        u32 v = au[(size_t)n * 64 + lane];
        sx += f16lo(v);
        sy += f16hi(v);
    }
    red[wave][lane * 2] = sx;
    red[wave][lane * 2 + 1] = sy;
    __syncthreads();
    if (wave == 0) {
        float a = red[0][lane * 2] + red[1][lane * 2] + red[2][lane * 2] + red[3][lane * 2];
        float b = red[0][lane * 2 + 1] + red[1][lane * 2 + 1] + red[2][lane * 2 + 1] +
                  red[3][lane * 2 + 1];
        atomicAdd(&pooled[g * 128 + lane * 2], a);
        atomicAdd(&pooled[g * 128 + lane * 2 + 1], b);
    }
}

// ---------------- final: one block per graph, K split over 4 groups + LDS reduce ----------
__global__ __launch_bounds__(256) void final_kernel(const float* __restrict__ pooled,
                                                    const int* __restrict__ gstart,
                                                    const float* __restrict__ out_w,
                                                    const float* __restrict__ out_b,
                                                    float* __restrict__ out) {
    __shared__ float red[256];
    const int g = blockIdx.x, tid = threadIdx.x;
    const int o = tid & 63, part = tid >> 6;   // 4 K-groups of 32
    float s = 0.f;
#pragma unroll
    for (int kk = 0; kk < 32; ++kk) {
        int k = part * 32 + kk;
        s += pooled[g * 128 + k] * out_w[k * 64 + o];
    }
    red[tid] = s;
    __syncthreads();
    if (part == 0) {
        float c = fmaxf((float)(gstart[g + 1] - gstart[g]), 1.0f);
        float tot = red[o] + red[o + 64] + red[o + 128] + red[o + 192];
        out[g * 64 + o] = tot / c + out_b[o];
    }
}

extern "C" void kernel_launch(void* const* d_in, const int* in_sizes, int n_in, void* d_out,
                              int out_size, void* d_ws, size_t ws_size, hipStream_t stream) {
    const float* x = (const float*)d_in[0];
    const int* ei = (const int*)d_in[1];
    const int* batch = (const int*)d_in[3];
    const float* cw[3][6];  // lin_w, lin_b, w1, b1, w2, b2
    for (int l = 0; l < 3; ++l)
        for (int j = 0; j < 6; ++j) cw[l][j] = (const float*)d_in[4 + l * 6 + j];
    const float* out_w = (const float*)d_in[22];
    const float* out_b = (const float*)d_in[23];
    float* out = (float*)d_out;

    const int N = in_sizes[0] / 128;
    const int E = in_sizes[1] / 2;
    const int G = out_size / 64;
    const int nbk = (N + 127) >> 7;
    const int NB = 416;
    const int cap = E / nbk + 512;
    const int nBat = (N + 255) / 256;

    // ---- workspace layout ----
    char* base = (char*)d_ws;
    size_t off = 0;
    auto alloc = [&](size_t b) { size_t o = off; off += (b + 255) & ~(size_t)255; return o; };
    float* pooled = (float*)(base + alloc((size_t)G * 128 * 4));
    int* done = (int*)(base + alloc(256));
    const size_t zero_bytes = off;
    int* gstart = (int*)(base + alloc((size_t)(G + 1) * 4));
    int* hist = (int*)(base + alloc((size_t)NB * nbk * 4));
    int* bcnt = (int*)(base + alloc((size_t)nbk * 4));
    int* bsumB = (int*)(base + alloc((size_t)nbk * 4));
    int* bbase = (int*)(base + alloc((size_t)nbk * 4));
    int* row_ptr = (int*)(base + alloc((size_t)(N + 1) * 4));
    float* cntp1f = (float*)(base + alloc((size_t)N * 4));
    u16* colarr = (u16*)(base + alloc((size_t)E * 2));
    u32* bbuf = (u32*)(base + alloc((size_t)nbk * cap * 4));
    f16_t* xb = (f16_t*)(base + alloc((size_t)N * 128 * 2));   // layer0 input / final output
    f16_t* q = (f16_t*)(base + alloc((size_t)N * 128 * 2));    // gather output
    f16_t* aArr = (f16_t*)(base + alloc((size_t)N * 128 * 2)); // a-half of edge operand
    u8* b8 = (u8*)(base + alloc((size_t)N * 128));             // b-half, fp8 e4m3
    f16_t* linw16 = (f16_t*)(base + alloc(3 * 16384 * 2));
    f16_t* w1T = (f16_t*)(base + alloc(3 * 32768 * 2));
    f16_t* W12ct = (f16_t*)(base + alloc(3 * 32768 * 2));
    f16_t* W2t = (f16_t*)(base + alloc(3 * 16384 * 2));
    float* bias256c = (float*)(base + alloc(3 * 256 * 4));
    (void)ws_size; (void)n_in;

    hipMemsetAsync(d_ws, 0, zero_bytes, stream);

    // fused prep
    PrepArgs pa;
    pa.x = x; pa.xb = xb; pa.totalx = N * 128;
    pa.ei = ei; pa.E = E;
    pa.hist = hist; pa.nbk = nbk; pa.NB = NB;
    pa.batch = batch; pa.gstart = gstart; pa.N = N; pa.G = G; pa.nBat = nBat;
    for (int l = 0; l < 3; ++l) {
        pa.lin_w[l] = cw[l][0]; pa.lin_b[l] = cw[l][1];
        pa.w1[l] = cw[l][2]; pa.b1[l] = cw[l][3]; pa.w2[l] = cw[l][4];
    }
    pa.linw16 = linw16; pa.w1T = w1T; pa.W2t = W2t; pa.bias256c = bias256c;
    const int nConvB = (N * 128 / 4 + 255) / 256;
    prep_kernel<<<9 + 48 + 3 + NB + nBat + nConvB, 256, 0, stream>>>(pa, nConvB);

    // compose W12c with MFMA (6 blocks)
    compose_kernel<<<6, 256, 0, stream>>>(w1T, linw16, W12ct);

    // CSR: deterministic counting sort (scanb inlined into part2's last-finisher)
    hscan_kernel<<<nbk, 256, 0, stream>>>(hist, bcnt, nbk, NB);
    scat_kernel<<<NB, 256, 0, stream>>>(ei, hist, bbuf, E, NB, nbk, cap);
    part2_kernel<<<nbk, 128, 0, stream>>>(bbuf, bcnt, row_ptr, cntp1f, bsumB, bbase, done,
                                          cap, N, nbk);
    part3_kernel<<<nbk, 128, 0, stream>>>(bbuf, bcnt, bbase, row_ptr, colarr, cap, N);

    const int ntiles = (N + 127) >> 7;
    const int pgrid = (ntiles < 256) ? ntiles : 256;

    // layer 0 front half: [a|b8] = xb0 @ W12c0 + bias0
    gemm_persist<16><<<pgrid, 512, 0, stream>>>(xb, W12ct, bias256c, nullptr, nullptr,
                                                aArr, b8, N, 0, ntiles);
    // boundaries 0->1, 1->2 fused; layer 2 back half standalone (xb needed by pool)
    for (int l = 0; l < 3; ++l) {
        gather_kernel<<<(N * 64 + 255) / 256, 256, 0, stream>>>(aArr, b8, row_ptr, colarr, q, N);
        if (l < 2) {
            fused_g8_g16<<<pgrid, 512, 0, stream>>>(q, W2t + l * 16384, cw[l][5], cntp1f,
                                                    W12ct + (l + 1) * 32768,
                                                    bias256c + (l + 1) * 256, aArr, b8, N,
                                                    ntiles);
        } else {
            gemm_persist<8><<<pgrid, 512, 0, stream>>>(q, W2t + l * 16384, nullptr, cw[l][5],
                                                       cntp1f, xb, nullptr, N, 1, ntiles);
        }
    }

    pool_kernel<<<G * 8, 256, 0, stream>>>(xb, gstart, pooled);
    final_kernel<<<G, 256, 0, stream>>>(pooled, gstart, out_w, out_b, out);
}

// Round 11
// 367.788 us; speedup vs baseline: 1.0488x; 1.0488x over previous
//
#include <hip/hip_runtime.h>
#include <hip/hip_bf16.h>

// MPNN on MI355X.
// Identities: (1) (sum_e relu(a+b)) @ w2 pulls w2 out of the edge sum; (2) lin GEMM composed
// into w1 GEMM via W12c = lin_w@w1 (MFMA compose_kernel).
// b-half of the edge operand stored FP8 e4m3 (6.4MB working set); a f16; accumulate f32.
// CSR: deterministic counting sort (LDS-rank, bucket-local). Atomic CSR regressed (R15).
// R11: glds16 staging. 483->409. R13: persistent 2-phase GEMMs ->388.
// R14: gather+gemm8 tile-fusion regressed (gather is cross-row, needs max TLP). Reverted.
// R17: pool contention fix (1 atomic/col/block via gstart ranges). 413->379.6.
// R18: layer-boundary fusion gemm8(l)+gemm16(l+1) (xb never leaves LDS). ->369.7. BEST.
// R19 (gemm8+pool fusion, +8) and R20 (part2/scanb merge alone, +16 vs R18) both regressed;
// attributions mutually inconsistent -> either part2merge's 391 per-block threadfences are
// real cost, or run noise is +-8us. R21: byte-exact R18 restore as controlled re-measurement.

typedef _Float16 f16_t;
typedef f16_t f16x2 __attribute__((ext_vector_type(2)));
typedef f16_t f16x8 __attribute__((ext_vector_type(8)));
typedef float f32x4 __attribute__((ext_vector_type(4)));
typedef float f32x2v __attribute__((ext_vector_type(2)));
typedef unsigned int u32;
typedef unsigned short u16;
typedef unsigned char u8;

__device__ __forceinline__ float f16lo(u32 v) {
    return (float)__builtin_bit_cast(f16_t, (u16)(v & 0xffff));
}
__device__ __forceinline__ float f16hi(u32 v) {
    return (float)__builtin_bit_cast(f16_t, (u16)(v >> 16));
}
__device__ __forceinline__ u16 f16b(float x) { return __builtin_bit_cast(u16, (f16_t)x); }
__device__ __forceinline__ u32 f16pack(float x, float y) {
    return (u32)f16b(x) | ((u32)f16b(y) << 16);
}

// async global->LDS, 16B per lane; LDS dest must be wave-uniform base (+lane*16 implicit)
typedef __attribute__((address_space(1))) void gvoid_t;
typedef __attribute__((address_space(3))) void lvoid_t;
__device__ __forceinline__ void glds16(const void* g, void* l) {
    __builtin_amdgcn_global_load_lds((gvoid_t*)g, (lvoid_t*)l, 16, 0, 0);
}

// ---------------- fused prep: transposes | lin_w->f16 | bias | hist | gstart | convx -------
struct PrepArgs {
    const float* x; f16_t* xb; int totalx;
    const int* ei; int E;
    int* hist; int nbk; int NB;
    const int* batch; int* gstart; int N; int G; int nBat;
    const float* lin_w[3]; const float* lin_b[3];
    const float* w1[3]; const float* b1[3]; const float* w2[3];
    f16_t* linw16;   // [3][128][128] f16 copy of lin_w
    f16_t* w1T;      // [3][256][128]: w1T[j][c] = w1sel(c,j)
    f16_t* W2t;      // [3][128][128]: W2t[j][k] = w2[k][j]
    float* bias256c; // [3][256]
};

__global__ __launch_bounds__(256) void prep_kernel(PrepArgs A, int nConvB) {
    __shared__ union { int hist[512]; u16 T16[128 * 130]; } shm;
    const int b = blockIdx.x, tid = threadIdx.x;
    const int nTr = 9, nLw = 48, nBias = 3;
    if (b < nTr) {
        // LDS-tiled 128x128 transpose -> f16. which: 0=w1 top, 1=w1 bottom, 2=w2
        int layer = b / 3, which = b % 3;
        const float* src; f16_t* dst;
        if (which == 0)      { src = A.w1[layer];          dst = A.w1T + layer * 32768; }
        else if (which == 1) { src = A.w1[layer] + 16384;  dst = A.w1T + layer * 32768 + 16384; }
        else                 { src = A.w2[layer];          dst = A.W2t + layer * 16384; }
#pragma unroll
        for (int it = 0; it < 16; ++it) {
            int idx = it * 1024 + tid * 4;     // coalesced float4 read
            int r = idx >> 7, c = idx & 127;
            float4 v = *(const float4*)(src + idx);
            *(u32*)&shm.T16[r * 130 + c] = f16pack(v.x, v.y);
            *(u32*)&shm.T16[r * 130 + c + 2] = f16pack(v.z, v.w);
        }
        __syncthreads();
#pragma unroll
        for (int it = 0; it < 32; ++it) {      // 32*256 = 8192 u32 outputs
            int o = it * 256 + tid;            // u32 output index: j*64 + c2
            int j = o >> 6, c = (o & 63) * 2;
            u32 w = (u32)shm.T16[c * 130 + j] | ((u32)shm.T16[(c + 1) * 130 + j] << 16);
            ((u32*)dst)[o] = w;                // dst[j][c], coalesced
        }
        return;
    }
    if (b < nTr + nLw) {
        int i = (b - nTr) * 1024 + tid * 4;    // over 3*16384 f32
        int layer = i >> 14, off = i & 16383;
        float4 v = *(const float4*)(A.lin_w[layer] + off);
        *(uint2*)(A.linw16 + i) = make_uint2(f16pack(v.x, v.y), f16pack(v.z, v.w));
        return;
    }
    if (b < nTr + nLw + nBias) {
        int layer = b - nTr - nLw;
        int j = tid;  // 256 threads
        const float* w1p = A.w1[layer];
        const float* wcol = (j < 128) ? (w1p + j) : (w1p + 16384 + (j - 128));
        const float* lbp = A.lin_b[layer];
        float s = (j < 128) ? A.b1[layer][j] : 0.f;
        for (int c = 0; c < 128; ++c) s += lbp[c] * wcol[c * 128];  // coalesced across lanes
        A.bias256c[layer * 256 + j] = s;
        return;
    }
    if (b < nTr + nLw + nBias + A.NB) {
        // edge histogram: bucket = dst>>7, LDS counters only
        const int bb = b - nTr - nLw - nBias;
        const int nbk = A.nbk, E = A.E;
        for (int i = tid; i < nbk; i += 256) shm.hist[i] = 0;
        __syncthreads();
        const int chunk = (E + A.NB - 1) / A.NB;
        const int e0 = bb * chunk, e1 = min(E, e0 + chunk);
        for (int e = e0 + tid; e < e1; e += 256) atomicAdd(&shm.hist[A.ei[E + e] >> 7], 1);
        __syncthreads();
        for (int i = tid; i < nbk; i += 256) A.hist[(size_t)bb * nbk + i] = shm.hist[i];
        return;
    }
    if (b < nTr + nLw + nBias + A.NB + A.nBat) {
        // gstart[g] = first node of graph g (batch sorted). Transition scan.
        int n = (b - nTr - nLw - nBias - A.NB) * 256 + tid;
        if (n >= A.N) return;
        int b1 = A.batch[n];
        if (n == 0) {
            for (int g = 0; g <= b1; ++g) A.gstart[g] = 0;
        } else {
            int b0 = A.batch[n - 1];
            if (b0 != b1)
                for (int g = b0 + 1; g <= b1; ++g) A.gstart[g] = n;
        }
        if (n == A.N - 1)
            for (int g = b1 + 1; g <= A.G; ++g) A.gstart[g] = A.N;
        return;
    }
    // convx: fp32 -> f16
    int i = ((b - nTr - nLw - nBias - A.NB - A.nBat) * 256 + tid) * 4;
    if (i >= A.totalx) return;
    float4 v = *(const float4*)(A.x + i);
    *(uint2*)(A.xb + i) = make_uint2(f16pack(v.x, v.y), f16pack(v.z, v.w));
}

// ---------------- hscan: per-bucket exclusive scan of per-block counts ----------------
__global__ __launch_bounds__(256) void hscan_kernel(int* __restrict__ hist,
                                                    int* __restrict__ bcnt, int nbk, int NB) {
    __shared__ int sh[256];
    const int b = blockIdx.x, t = threadIdx.x;
    int run = 0;
    for (int c0 = 0; c0 < NB; c0 += 256) {
        int idx = c0 + t;
        int v = (idx < NB) ? hist[(size_t)idx * nbk + b] : 0;
        sh[t] = v;
        __syncthreads();
#pragma unroll
        for (int o = 1; o < 256; o <<= 1) {
            int u = (t >= o) ? sh[t - o] : 0;
            __syncthreads();
            sh[t] += u;
            __syncthreads();
        }
        if (idx < NB) hist[(size_t)idx * nbk + b] = run + sh[t] - v;
        int tot = sh[255];
        __syncthreads();
        run += tot;
    }
    if (t == 0) bcnt[b] = run;
}

// ---------------- scat: packed (dst&127)<<16|src at precomputed base + LDS rank ------------
__global__ __launch_bounds__(256) void scat_kernel(const int* __restrict__ ei,
                                                   const int* __restrict__ hist,
                                                   u32* __restrict__ bbuf, int E, int NB,
                                                   int nbk, int cap) {
    __shared__ int basep[512];
    __shared__ int cnt2[512];
    const int bb = blockIdx.x, t = threadIdx.x;
    for (int i = t; i < nbk; i += 256) {
        basep[i] = hist[(size_t)bb * nbk + i];
        cnt2[i] = 0;
    }
    __syncthreads();
    const int chunk = (E + NB - 1) / NB;
    const int e0 = bb * chunk, e1 = min(E, e0 + chunk);
    for (int e = e0 + t; e < e1; e += 256) {
        int dst = ei[E + e], src = ei[e];
        int bkt = dst >> 7;
        int r = atomicAdd(&cnt2[bkt], 1);  // LDS returning atomic: cheap
        int pp = basep[bkt] + r;
        if (pp < cap) bbuf[(size_t)bkt * cap + pp] = ((u32)(dst & 127) << 16) | (u32)src;
    }
}

// ---------------- part2: per-bucket degree + local scan ----------------
__global__ __launch_bounds__(128) void part2_kernel(const u32* __restrict__ bbuf,
                                                    const int* __restrict__ bcnt,
                                                    int* __restrict__ row_ptr,
                                                    float* __restrict__ cntp1f,
                                                    int* __restrict__ bsumB, int cap, int N) {
    __shared__ int ldeg[128];
    __shared__ int sh[128];
    const int b = blockIdx.x, t = threadIdx.x;
    ldeg[t] = 0;
    __syncthreads();
    const int cnt = min(bcnt[b], cap);
    const u32* p = bbuf + (size_t)b * cap;
    for (int i = t; i < cnt; i += 128) atomicAdd(&ldeg[p[i] >> 16], 1);
    __syncthreads();
    int d = ldeg[t];
    sh[t] = d;
    __syncthreads();
#pragma unroll
    for (int o = 1; o < 128; o <<= 1) {
        int u = (t >= o) ? sh[t - o] : 0;
        __syncthreads();
        sh[t] += u;
        __syncthreads();
    }
    int node = (b << 7) + t;
    if (node < N) {
        row_ptr[node] = sh[t] - d;
        cntp1f[node] = (float)(d + 1);
    }
    if (t == 127) bsumB[b] = sh[127];
}

// ---------------- scanB: exclusive scan of bucket totals (1 block) ----------------
__global__ __launch_bounds__(512) void scanb_kernel(const int* __restrict__ bsumB,
                                                    int* __restrict__ bbase,
                                                    int* __restrict__ row_ptr, int nbk, int N) {
    __shared__ int sh[512];
    const int t = threadIdx.x;
    int v = (t < nbk) ? bsumB[t] : 0;
    sh[t] = v;
    __syncthreads();
#pragma unroll
    for (int o = 1; o < 512; o <<= 1) {
        int u = (t >= o) ? sh[t - o] : 0;
        __syncthreads();
        sh[t] += u;
        __syncthreads();
    }
    if (t < nbk) bbase[t] = sh[t] - v;
    if (t == 511) row_ptr[N] = sh[511];
}

// ---------------- part3: finalize row_ptr, scatter u16 colarr ----------------
__global__ __launch_bounds__(128) void part3_kernel(const u32* __restrict__ bbuf,
                                                    const int* __restrict__ bcnt,
                                                    const int* __restrict__ bbase,
                                                    int* __restrict__ row_ptr,
                                                    u16* __restrict__ colarr, int cap, int N) {
    __shared__ int lcur[128];
    const int b = blockIdx.x, t = threadIdx.x;
    const int node = (b << 7) + t;
    const int bb = bbase[b];
    int rp = 0;
    if (node < N) {
        rp = row_ptr[node] + bb;
        row_ptr[node] = rp;
    }
    lcur[t] = rp;
    __syncthreads();
    const int cnt = min(bcnt[b], cap);
    const u32* p = bbuf + (size_t)b * cap;
    for (int i = t; i < cnt; i += 128) {
        u32 en = p[i];
        int addr = atomicAdd(&lcur[en >> 16], 1);
        colarr[addr] = (u16)(en & 0xffffu);
    }
}

// ---------------- one-shot MFMA tile (compose only): Y[128x128] = X @ Wt^T -----------------
__device__ __forceinline__ void gemm_tile(const f16_t* __restrict__ X,
                                          const f16_t* __restrict__ Wt,
                                          f16_t* __restrict__ Y, int N,
                                          int ldc, int row0) {
    __shared__ f16_t sX[128 * 128];
    __shared__ f16_t sW[128 * 128];
    const int tid = threadIdx.x;
    const int wave = tid >> 6, lane = tid & 63;
#pragma unroll
    for (int it = 0; it < 8; ++it) {
        int idx = it * 256 + tid;
        int r = idx >> 4, c8 = idx & 15;
        int gr = row0 + r;
        if (gr >= N) gr = 0;
        glds16(X + (size_t)gr * 128 + ((c8 ^ (r & 7)) * 8),
               sX + (size_t)(it * 256 + (wave << 6)) * 8);
    }
#pragma unroll
    for (int it = 0; it < 8; ++it) {
        int idx = it * 256 + tid;
        int r = idx >> 4, c8 = idx & 15;
        glds16(Wt + (size_t)r * 128 + ((c8 ^ (r & 7)) * 8),
               sW + (size_t)(it * 256 + (wave << 6)) * 8);
    }
    __syncthreads();
    const int m = lane & 15, q = lane >> 4;
    const int sw = m & 7;
    f32x4 acc[2][8];
#pragma unroll
    for (int rt = 0; rt < 2; ++rt)
#pragma unroll
        for (int t = 0; t < 8; ++t) acc[rt][t] = (f32x4){0.f, 0.f, 0.f, 0.f};
#pragma unroll
    for (int kk = 0; kk < 4; ++kk) {
        const int g = (kk * 4 + q) ^ sw;
        f16x8 a0 = *(const f16x8*)(&sX[(wave * 32 + m) * 128 + g * 8]);
        f16x8 a1 = *(const f16x8*)(&sX[(wave * 32 + 16 + m) * 128 + g * 8]);
#pragma unroll
        for (int t = 0; t < 8; ++t) {
            f16x8 bfr = *(const f16x8*)(&sW[(t * 16 + m) * 128 + g * 8]);
            acc[0][t] = __builtin_amdgcn_mfma_f32_16x16x32_f16(a0, bfr, acc[0][t], 0, 0, 0);
            acc[1][t] = __builtin_amdgcn_mfma_f32_16x16x32_f16(a1, bfr, acc[1][t], 0, 0, 0);
        }
    }
#pragma unroll
    for (int t = 0; t < 8; ++t) {
        int col = t * 16 + m;
#pragma unroll
        for (int rt = 0; rt < 2; ++rt) {
#pragma unroll
            for (int j = 0; j < 4; ++j) {
                int r = row0 + wave * 32 + rt * 16 + q * 4 + j;
                if (r < N) Y[(size_t)r * ldc + col] = (f16_t)acc[rt][t][j];
            }
        }
    }
}

// compose: W12ct[layer][j][k] = sum_c w1T[layer][j][c] * linw16[layer][k][c]  (MFMA)
__global__ __launch_bounds__(256) void compose_kernel(const f16_t* __restrict__ w1T,
                                                      const f16_t* __restrict__ linw16,
                                                      f16_t* __restrict__ W12ct) {
    int layer = blockIdx.x >> 1, rb = blockIdx.x & 1;
    gemm_tile(w1T + layer * 32768, linw16 + layer * 16384, W12ct + layer * 32768, 256, 128,
              rb * 128);
}

// ---------------- persistent 2-phase node GEMM ----------------
// NT=16: Y[N][0..127]=f16 aArr, cols 128..255 -> fp8 Y8. NT=8: Y[N][0..127] f16 only.
template <int NT>
__global__ __launch_bounds__(512, 1) void gemm_persist(
    const f16_t* __restrict__ X, const f16_t* __restrict__ Wt,
    const float* __restrict__ bias, const float* __restrict__ bias2,
    const float* __restrict__ rowscale, f16_t* __restrict__ Y, u8* __restrict__ Y8,
    int N, int relu_flag, int ntiles) {
    __shared__ f16_t sW[NT * 16 * 128];
    __shared__ f16_t sX[2][128 * 128];
    const int tid = threadIdx.x;
    const int wave = tid >> 6, lane = tid & 63;
    const int m = lane & 15, q = lane >> 4, sw = m & 7;
    constexpr int NR = (NT == 16) ? 2 : 1;
    const int rb0 = (NT == 16) ? ((wave & 3) * 32) : (wave * 16);
    const int chalf = (NT == 16) ? (wave >> 2) : 0;

    // stage W once (resident for whole kernel). NT*16 rows x 16 chunks = NT/2 * 512 chunks.
#pragma unroll
    for (int it = 0; it < NT / 2; ++it) {
        int idx = it * 512 + tid;
        int r = idx >> 4, c8 = idx & 15;
        glds16(Wt + (size_t)r * 128 + ((c8 ^ (r & 7)) * 8),
               sW + (size_t)(it * 512 + (wave << 6)) * 8);
    }
    // hoist per-lane column bias (tile-invariant)
    float bvv[8], b2vv[8];
#pragma unroll
    for (int t2 = 0; t2 < 8; ++t2) {
        int colb = chalf * 128 + t2 * 16 + m;
        bvv[t2] = bias ? bias[colb] : 0.f;
        b2vv[t2] = bias2 ? bias2[colb] : 0.f;
    }
    // stage first tile into buf0
    int t = blockIdx.x;
    {
        int row0 = t * 128;
#pragma unroll
        for (int it = 0; it < 4; ++it) {
            int idx = it * 512 + tid;
            int r = idx >> 4, c8 = idx & 15;
            int gr = row0 + r;
            if (gr >= N) gr = 0;
            glds16(X + (size_t)gr * 128 + ((c8 ^ (r & 7)) * 8),
                   sX[0] + (size_t)(it * 512 + (wave << 6)) * 8);
        }
    }
    __syncthreads();
    int cur = 0;
    for (; t < ntiles; t += gridDim.x) {
        const int row0 = t * 128;
        const int tn = t + gridDim.x;
        f16_t* sXc = sX[cur];
        if (tn < ntiles) {  // prefetch next tile while computing this one
            const int r0n = tn * 128;
            f16_t* sXn = sX[cur ^ 1];
#pragma unroll
            for (int it = 0; it < 4; ++it) {
                int idx = it * 512 + tid;
                int r = idx >> 4, c8 = idx & 15;
                int gr = r0n + r;
                if (gr >= N) gr = 0;
                glds16(X + (size_t)gr * 128 + ((c8 ^ (r & 7)) * 8),
                       sXn + (size_t)(it * 512 + (wave << 6)) * 8);
            }
        }
        f32x4 acc[NR][8];
#pragma unroll
        for (int rt = 0; rt < NR; ++rt)
#pragma unroll
            for (int t2 = 0; t2 < 8; ++t2) acc[rt][t2] = (f32x4){0.f, 0.f, 0.f, 0.f};
#pragma unroll
        for (int kk = 0; kk < 4; ++kk) {
            const int g = (kk * 4 + q) ^ sw;
            f16x8 a0 = *(const f16x8*)(&sXc[(rb0 + m) * 128 + g * 8]);
            f16x8 a1{};
            if constexpr (NR == 2) a1 = *(const f16x8*)(&sXc[(rb0 + 16 + m) * 128 + g * 8]);
#pragma unroll
            for (int t2 = 0; t2 < 8; ++t2) {
                f16x8 bfr =
                    *(const f16x8*)(&sW[(size_t)(chalf * 128 + t2 * 16 + m) * 128 + g * 8]);
                acc[0][t2] = __builtin_amdgcn_mfma_f32_16x16x32_f16(a0, bfr, acc[0][t2], 0, 0, 0);
                if constexpr (NR == 2)
                    acc[1][t2] =
                        __builtin_amdgcn_mfma_f32_16x16x32_f16(a1, bfr, acc[1][t2], 0, 0, 0);
            }
        }
        if (NT == 16) __syncthreads();  // waves w and w+4 share X rows: wait before overwrite
        // epilogue: wave-private 16-row LDS region in the consumed buffer, vector stores
        f16_t* region = sXc + wave * 16 * 128;
#pragma unroll
        for (int rt = 0; rt < NR; ++rt) {
            float rs[4];
#pragma unroll
            for (int j = 0; j < 4; ++j) {
                int gr = row0 + rb0 + rt * 16 + q * 4 + j;
                rs[j] = (bias2 && gr < N) ? rowscale[gr] : 0.f;
            }
#pragma unroll
            for (int t2 = 0; t2 < 8; ++t2) {
#pragma unroll
                for (int j = 0; j < 4; ++j) {
                    int rl2 = q * 4 + j;
                    float v = acc[rt][t2][j] + bvv[t2];
                    if (bias2) v += rs[j] * b2vv[t2];
                    if (relu_flag) v = fmaxf(v, 0.f);
                    region[rl2 * 128 + ((t2 * 16 + m) ^ ((rl2 & 4) << 3))] = (f16_t)v;
                }
            }
#pragma unroll
            for (int it2 = 0; it2 < 4; ++it2) {
                int i = it2 * 64 + lane;
                int rl = i >> 4, c8 = i & 15;
                int gr = row0 + rb0 + rt * 16 + rl;
                const f16_t* rp = &region[rl * 128 + ((c8 ^ (rl & 4)) * 8)];
                if (NT == 16 && chalf == 1) {
                    const u32* p = (const u32*)rp;
                    u32 lo = __builtin_amdgcn_cvt_pk_fp8_f32(f16lo(p[0]), f16hi(p[0]), 0u, false);
                    lo = __builtin_amdgcn_cvt_pk_fp8_f32(f16lo(p[1]), f16hi(p[1]), lo, true);
                    u32 hi = __builtin_amdgcn_cvt_pk_fp8_f32(f16lo(p[2]), f16hi(p[2]), 0u, false);
                    hi = __builtin_amdgcn_cvt_pk_fp8_f32(f16lo(p[3]), f16hi(p[3]), hi, true);
                    if (gr < N) *(uint2*)(Y8 + (size_t)gr * 128 + c8 * 8) = make_uint2(lo, hi);
                } else {
                    uint4 v4 = *(const uint4*)rp;
                    if (gr < N) *(uint4*)(Y + (size_t)gr * 128 + c8 * 8) = v4;
                }
            }
        }
        __syncthreads();  // drains prefetch vmcnt + syncs epilogue before next overwrite
        cur ^= 1;
    }
}

// -------- fused layer boundary: xb=relu(q@W2t+(deg+1)b2) -> [a|b8]=xb@W12c+bias ----------
// Both GEMMs are row-local, so one q tile flows through both without touching HBM.
// Phase B epilogue writes xb into sX using the staging layout: element (r,c) at
// LDS[r*128 + ((c/8 ^ (r&7))*8 + c%8)], so Phase C's standard A-fragment reads are legal.
__global__ __launch_bounds__(512, 1) void fused_g8_g16(
    const f16_t* __restrict__ q, const f16_t* __restrict__ W2t,
    const float* __restrict__ b2, const float* __restrict__ cntp1f,
    const f16_t* __restrict__ W12ct, const float* __restrict__ bias16,
    f16_t* __restrict__ aArr, u8* __restrict__ Y8, int N, int ntiles) {
    __shared__ f16_t sW2[128 * 128];    // 32KB, resident
    __shared__ f16_t sW12[256 * 128];   // 64KB, resident
    __shared__ f16_t sX[128 * 128];     // 32KB, per-tile (q -> xb -> epilogue scratch)
    const int tid = threadIdx.x;
    const int wave = tid >> 6, lane = tid & 63;
    const int m = lane & 15, qd = lane >> 4, sw = m & 7;
    const int chalf = wave >> 2, rb0c = (wave & 3) * 32;

    // stage both W's once
#pragma unroll
    for (int it = 0; it < 4; ++it) {
        int idx = it * 512 + tid;
        int r = idx >> 4, c8 = idx & 15;
        glds16(W2t + (size_t)r * 128 + ((c8 ^ (r & 7)) * 8),
               sW2 + (size_t)(it * 512 + (wave << 6)) * 8);
    }
#pragma unroll
    for (int it = 0; it < 8; ++it) {
        int idx = it * 512 + tid;
        int r = idx >> 4, c8 = idx & 15;
        glds16(W12ct + (size_t)r * 128 + ((c8 ^ (r & 7)) * 8),
               sW12 + (size_t)(it * 512 + (wave << 6)) * 8);
    }
    // hoist biases
    float b2v[8], bv16[8];
#pragma unroll
    for (int t2 = 0; t2 < 8; ++t2) {
        b2v[t2] = b2[t2 * 16 + m];
        bv16[t2] = bias16[chalf * 128 + t2 * 16 + m];
    }

    for (int t = blockIdx.x; t < ntiles; t += gridDim.x) {
        const int row0 = t * 128;
        // stage q tile
#pragma unroll
        for (int it = 0; it < 4; ++it) {
            int idx = it * 512 + tid;
            int r = idx >> 4, c8 = idx & 15;
            int gr = row0 + r;
            if (gr >= N) gr = 0;
            glds16(q + (size_t)gr * 128 + ((c8 ^ (r & 7)) * 8),
                   sX + (size_t)(it * 512 + (wave << 6)) * 8);
        }
        __syncthreads();  // drains q (and W on first iteration)

        // ---- Phase B: xb rows wave*16..+15 = relu(q @ W2t + (deg+1)*b2) ----
        f32x4 accB[8];
#pragma unroll
        for (int t2 = 0; t2 < 8; ++t2) accB[t2] = (f32x4){0.f, 0.f, 0.f, 0.f};
#pragma unroll
        for (int kk = 0; kk < 4; ++kk) {
            const int g = (kk * 4 + qd) ^ sw;
            f16x8 a0 = *(const f16x8*)(&sX[(wave * 16 + m) * 128 + g * 8]);
#pragma unroll
            for (int t2 = 0; t2 < 8; ++t2) {
                f16x8 bfr = *(const f16x8*)(&sW2[(t2 * 16 + m) * 128 + g * 8]);
                accB[t2] = __builtin_amdgcn_mfma_f32_16x16x32_f16(a0, bfr, accB[t2], 0, 0, 0);
            }
        }
        // epilogue B: write xb into own rows of sX in staging layout (own A-reads are done)
        float rs[4];
#pragma unroll
        for (int j = 0; j < 4; ++j) {
            int gr = row0 + wave * 16 + qd * 4 + j;
            rs[j] = (gr < N) ? cntp1f[gr] : 0.f;
        }
#pragma unroll
        for (int t2 = 0; t2 < 8; ++t2) {
#pragma unroll
            for (int j = 0; j < 4; ++j) {
                int rr = wave * 16 + qd * 4 + j;
                float v = fmaxf(accB[t2][j] + rs[j] * b2v[t2], 0.f);
                sX[rr * 128 + (((2 * t2 + (m >> 3)) ^ (rr & 7)) * 8 + (m & 7))] = (f16_t)v;
            }
        }
        __syncthreads();  // xb tile visible to all waves

        // ---- Phase C: [a|b8] rows rb0c..+31, cols chalf*128..+127 = xb @ W12c + bias ----
        f32x4 accC[2][8];
#pragma unroll
        for (int rt = 0; rt < 2; ++rt)
#pragma unroll
            for (int t2 = 0; t2 < 8; ++t2) accC[rt][t2] = (f32x4){0.f, 0.f, 0.f, 0.f};
#pragma unroll
        for (int kk = 0; kk < 4; ++kk) {
            const int g = (kk * 4 + qd) ^ sw;
            f16x8 a0 = *(const f16x8*)(&sX[(rb0c + m) * 128 + g * 8]);
            f16x8 a1 = *(const f16x8*)(&sX[(rb0c + 16 + m) * 128 + g * 8]);
#pragma unroll
            for (int t2 = 0; t2 < 8; ++t2) {
                f16x8 bfr =
                    *(const f16x8*)(&sW12[(size_t)(chalf * 128 + t2 * 16 + m) * 128 + g * 8]);
                accC[0][t2] = __builtin_amdgcn_mfma_f32_16x16x32_f16(a0, bfr, accC[0][t2], 0, 0, 0);
                accC[1][t2] = __builtin_amdgcn_mfma_f32_16x16x32_f16(a1, bfr, accC[1][t2], 0, 0, 0);
            }
        }
        __syncthreads();  // all xb reads done before scratch overwrite

        // epilogue C: wave-private 16-row scratch region, vector stores (same as persist<16>)
        f16_t* region = sX + wave * 16 * 128;
#pragma unroll
        for (int rt = 0; rt < 2; ++rt) {
#pragma unroll
            for (int t2 = 0; t2 < 8; ++t2) {
#pragma unroll
                for (int j = 0; j < 4; ++j) {
                    int rl2 = qd * 4 + j;
                    float v = accC[rt][t2][j] + bv16[t2];
                    region[rl2 * 128 + ((t2 * 16 + m) ^ ((rl2 & 4) << 3))] = (f16_t)v;
                }
            }
#pragma unroll
            for (int it2 = 0; it2 < 4; ++it2) {
                int i = it2 * 64 + lane;
                int rl = i >> 4, c8 = i & 15;
                int gr = row0 + rb0c + rt * 16 + rl;
                const f16_t* rp = &region[rl * 128 + ((c8 ^ (rl & 4)) * 8)];
                if (chalf == 1) {
                    const u32* p = (const u32*)rp;
                    u32 lo = __builtin_amdgcn_cvt_pk_fp8_f32(f16lo(p[0]), f16hi(p[0]), 0u, false);
                    lo = __builtin_amdgcn_cvt_pk_fp8_f32(f16lo(p[1]), f16hi(p[1]), lo, true);
                    u32 hi = __builtin_amdgcn_cvt_pk_fp8_f32(f16lo(p[2]), f16hi(p[2]), 0u, false);
                    hi = __builtin_amdgcn_cvt_pk_fp8_f32(f16lo(p[3]), f16hi(p[3]), hi, true);
                    if (gr < N) *(uint2*)(Y8 + (size_t)gr * 128 + c8 * 8) = make_uint2(lo, hi);
                } else {
                    uint4 v4 = *(const uint4*)rp;
                    if (gr < N) *(uint4*)(aArr + (size_t)gr * 128 + c8 * 8) = v4;
                }
            }
        }
        __syncthreads();  // scratch free before next tile staging
    }
}

// ---------------- gather: a f16, b fp8, f32 accum; predicated 16-wide (4 loads deep) -------
__global__ __launch_bounds__(256) void gather_kernel(const f16_t* __restrict__ aArr,
                                                     const u8* __restrict__ b8,
                                                     const int* __restrict__ row_ptr,
                                                     const u16* __restrict__ colarr,
                                                     f16_t* __restrict__ q, int N) {
    int wid = (blockIdx.x * 256 + threadIdx.x) >> 6;
    int lane = threadIdx.x & 63;
    if (wid >= N) return;
    const int g = lane >> 4, l = lane & 15;
    uint4 A = ((const uint4*)aArr)[(size_t)wid * 16 + l];
    float a0 = f16lo(A.x), a1 = f16hi(A.x), a2 = f16lo(A.y), a3 = f16hi(A.y);
    float a4 = f16lo(A.z), a5 = f16hi(A.z), a6 = f16lo(A.w), a7 = f16hi(A.w);
    float c0 = 0.f, c1 = 0.f, c2 = 0.f, c3 = 0.f, c4 = 0.f, c5 = 0.f, c6 = 0.f, c7 = 0.f;
    const uint2* b8u = (const uint2*)b8;  // row = 16 uint2
    auto accum = [&](uint2 B) {
        f32x2v p0 = __builtin_amdgcn_cvt_pk_f32_fp8(B.x, false);
        f32x2v p1 = __builtin_amdgcn_cvt_pk_f32_fp8(B.x, true);
        f32x2v p2 = __builtin_amdgcn_cvt_pk_f32_fp8(B.y, false);
        f32x2v p3 = __builtin_amdgcn_cvt_pk_f32_fp8(B.y, true);
        c0 += fmaxf(a0 + p0.x, 0.f); c1 += fmaxf(a1 + p0.y, 0.f);
        c2 += fmaxf(a2 + p1.x, 0.f); c3 += fmaxf(a3 + p1.y, 0.f);
        c4 += fmaxf(a4 + p2.x, 0.f); c5 += fmaxf(a5 + p2.y, 0.f);
        c6 += fmaxf(a6 + p3.x, 0.f); c7 += fmaxf(a7 + p3.y, 0.f);
    };
    if (g == 0) accum(b8u[(size_t)wid * 16 + l]);  // self loop
    const int e0 = row_ptr[wid], e1 = row_ptr[wid + 1];
    for (int e = e0; e < e1; e += 16) {  // predicated: always 4 colarr+4 row loads in flight
#pragma unroll
        for (int s = 0; s < 4; ++s) {
            int idx = e + s * 4 + g;
            int src = colarr[min(idx, e1 - 1)];        // clamped: always a valid edge
            uint2 B = b8u[(size_t)src * 16 + l];
            if (idx < e1) accum(B);                    // masked accumulate
        }
    }
#pragma unroll
    for (int off = 16; off < 64; off <<= 1) {
        c0 += __shfl_xor(c0, off); c1 += __shfl_xor(c1, off);
        c2 += __shfl_xor(c2, off); c3 += __shfl_xor(c3, off);
        c4 += __shfl_xor(c4, off); c5 += __shfl_xor(c5, off);
        c6 += __shfl_xor(c6, off); c7 += __shfl_xor(c7, off);
    }
    if (g == 0) {
        uint4 o;
        o.x = f16pack(c0, c1); o.y = f16pack(c2, c3);
        o.z = f16pack(c4, c5); o.w = f16pack(c6, c7);
        ((uint4*)q)[(size_t)wid * 16 + l] = o;
    }
}

// ---------------- pooling: 8 blocks/graph, contiguous streaming, 1 atomic/col/block -------
__global__ __launch_bounds__(256) void pool_kernel(const f16_t* __restrict__ agg,
                                                   const int* __restrict__ gstart,
                                                   float* __restrict__ pooled) {
    __shared__ float red[4][128];
    const int g = blockIdx.x >> 3, part = blockIdx.x & 7;
    const int tid = threadIdx.x, wave = tid >> 6, lane = tid & 63;
    const int lo = gstart[g], hi = gstart[g + 1];
    const int cnt = hi - lo;
    const int len = (cnt + 7) >> 3;
    const int n0 = lo + part * len, n1 = min(hi, n0 + len);
    const u32* au = (const u32*)agg;
    float sx = 0.f, sy = 0.f;
#pragma unroll 4
    for (int n = n0 + wave; n < n1; n += 4) {
        u32 v = au[(size_t)n * 64 + lane];
        sx += f16lo(v);
        sy += f16hi(v);
    }
    red[wave][lane * 2] = sx;
    red[wave][lane * 2 + 1] = sy;
    __syncthreads();
    if (wave == 0) {
        float a = red[0][lane * 2] + red[1][lane * 2] + red[2][lane * 2] + red[3][lane * 2];
        float b = red[0][lane * 2 + 1] + red[1][lane * 2 + 1] + red[2][lane * 2 + 1] +
                  red[3][lane * 2 + 1];
        atomicAdd(&pooled[g * 128 + lane * 2], a);
        atomicAdd(&pooled[g * 128 + lane * 2 + 1], b);
    }
}

// ---------------- final: one block per graph, K split over 4 groups + LDS reduce ----------
__global__ __launch_bounds__(256) void final_kernel(const float* __restrict__ pooled,
                                                    const int* __restrict__ gstart,
                                                    const float* __restrict__ out_w,
                                                    const float* __restrict__ out_b,
                                                    float* __restrict__ out) {
    __shared__ float red[256];
    const int g = blockIdx.x, tid = threadIdx.x;
    const int o = tid & 63, part = tid >> 6;   // 4 K-groups of 32
    float s = 0.f;
#pragma unroll
    for (int kk = 0; kk < 32; ++kk) {
        int k = part * 32 + kk;
        s += pooled[g * 128 + k] * out_w[k * 64 + o];
    }
    red[tid] = s;
    __syncthreads();
    if (part == 0) {
        float c = fmaxf((float)(gstart[g + 1] - gstart[g]), 1.0f);
        float tot = red[o] + red[o + 64] + red[o + 128] + red[o + 192];
        out[g * 64 + o] = tot / c + out_b[o];
    }
}

extern "C" void kernel_launch(void* const* d_in, const int* in_sizes, int n_in, void* d_out,
                              int out_size, void* d_ws, size_t ws_size, hipStream_t stream) {
    const float* x = (const float*)d_in[0];
    const int* ei = (const int*)d_in[1];
    const int* batch = (const int*)d_in[3];
    const float* cw[3][6];  // lin_w, lin_b, w1, b1, w2, b2
    for (int l = 0; l < 3; ++l)
        for (int j = 0; j < 6; ++j) cw[l][j] = (const float*)d_in[4 + l * 6 + j];
    const float* out_w = (const float*)d_in[22];
    const float* out_b = (const float*)d_in[23];
    float* out = (float*)d_out;

    const int N = in_sizes[0] / 128;
    const int E = in_sizes[1] / 2;
    const int G = out_size / 64;
    const int nbk = (N + 127) >> 7;
    const int NB = 416;
    const int cap = E / nbk + 512;
    const int nBat = (N + 255) / 256;

    // ---- workspace layout ----
    char* base = (char*)d_ws;
    size_t off = 0;
    auto alloc = [&](size_t b) { size_t o = off; off += (b + 255) & ~(size_t)255; return o; };
    float* pooled = (float*)(base + alloc((size_t)G * 128 * 4));
    const size_t zero_bytes = off;
    int* gstart = (int*)(base + alloc((size_t)(G + 1) * 4));
    int* hist = (int*)(base + alloc((size_t)NB * nbk * 4));
    int* bcnt = (int*)(base + alloc((size_t)nbk * 4));
    int* bsumB = (int*)(base + alloc((size_t)nbk * 4));
    int* bbase = (int*)(base + alloc((size_t)nbk * 4));
    int* row_ptr = (int*)(base + alloc((size_t)(N + 1) * 4));
    float* cntp1f = (float*)(base + alloc((size_t)N * 4));
    u16* colarr = (u16*)(base + alloc((size_t)E * 2));
    u32* bbuf = (u32*)(base + alloc((size_t)nbk * cap * 4));
    f16_t* xb = (f16_t*)(base + alloc((size_t)N * 128 * 2));   // layer0 input / final output
    f16_t* q = (f16_t*)(base + alloc((size_t)N * 128 * 2));    // gather output
    f16_t* aArr = (f16_t*)(base + alloc((size_t)N * 128 * 2)); // a-half of edge operand
    u8* b8 = (u8*)(base + alloc((size_t)N * 128));             // b-half, fp8 e4m3
    f16_t* linw16 = (f16_t*)(base + alloc(3 * 16384 * 2));
    f16_t* w1T = (f16_t*)(base + alloc(3 * 32768 * 2));
    f16_t* W12ct = (f16_t*)(base + alloc(3 * 32768 * 2));
    f16_t* W2t = (f16_t*)(base + alloc(3 * 16384 * 2));
    float* bias256c = (float*)(base + alloc(3 * 256 * 4));
    (void)ws_size; (void)n_in;

    hipMemsetAsync(d_ws, 0, zero_bytes, stream);

    // fused prep
    PrepArgs pa;
    pa.x = x; pa.xb = xb; pa.totalx = N * 128;
    pa.ei = ei; pa.E = E;
    pa.hist = hist; pa.nbk = nbk; pa.NB = NB;
    pa.batch = batch; pa.gstart = gstart; pa.N = N; pa.G = G; pa.nBat = nBat;
    for (int l = 0; l < 3; ++l) {
        pa.lin_w[l] = cw[l][0]; pa.lin_b[l] = cw[l][1];
        pa.w1[l] = cw[l][2]; pa.b1[l] = cw[l][3]; pa.w2[l] = cw[l][4];
    }
    pa.linw16 = linw16; pa.w1T = w1T; pa.W2t = W2t; pa.bias256c = bias256c;
    const int nConvB = (N * 128 / 4 + 255) / 256;
    prep_kernel<<<9 + 48 + 3 + NB + nBat + nConvB, 256, 0, stream>>>(pa, nConvB);

    // compose W12c with MFMA (6 blocks)
    compose_kernel<<<6, 256, 0, stream>>>(w1T, linw16, W12ct);

    // CSR: deterministic counting sort
    hscan_kernel<<<nbk, 256, 0, stream>>>(hist, bcnt, nbk, NB);
    scat_kernel<<<NB, 256, 0, stream>>>(ei, hist, bbuf, E, NB, nbk, cap);
    part2_kernel<<<nbk, 128, 0, stream>>>(bbuf, bcnt, row_ptr, cntp1f, bsumB, cap, N);
    scanb_kernel<<<1, 512, 0, stream>>>(bsumB, bbase, row_ptr, nbk, N);
    part3_kernel<<<nbk, 128, 0, stream>>>(bbuf, bcnt, bbase, row_ptr, colarr, cap, N);

    const int ntiles = (N + 127) >> 7;
    const int pgrid = (ntiles < 256) ? ntiles : 256;

    // layer 0 front half: [a|b8] = xb0 @ W12c0 + bias0
    gemm_persist<16><<<pgrid, 512, 0, stream>>>(xb, W12ct, bias256c, nullptr, nullptr,
                                                aArr, b8, N, 0, ntiles);
    // boundaries 0->1 and 1->2 fused; layer 2 back half standalone (xb needed by pool)
    for (int l = 0; l < 3; ++l) {
        gather_kernel<<<(N * 64 + 255) / 256, 256, 0, stream>>>(aArr, b8, row_ptr, colarr, q, N);
        if (l < 2) {
            fused_g8_g16<<<pgrid, 512, 0, stream>>>(q, W2t + l * 16384, cw[l][5], cntp1f,
                                                    W12ct + (l + 1) * 32768,
                                                    bias256c + (l + 1) * 256, aArr, b8, N,
                                                    ntiles);
        } else {
            gemm_persist<8><<<pgrid, 512, 0, stream>>>(q, W2t + l * 16384, nullptr, cw[l][5],
                                                       cntp1f, xb, nullptr, N, 1, ntiles);
        }
    }

    pool_kernel<<<G * 8, 256, 0, stream>>>(xb, gstart, pooled);
    final_kernel<<<G, 256, 0, stream>>>(pooled, gstart, out_w, out_b, out);
}